// Round 11
// baseline (229.786 us; speedup 1.0000x reference)
//
#include <hip/hip_runtime.h>
#include <hip/hip_bf16.h>

// LightningAttention MI355X — round 11: single cooperative kernel (grid barrier),
// q' lives in LDS (no global round-trip), ctx/ksum via device atomics + agent-scope reloads.
// k_prep: W split-transpose, rope table, zero ctx/ksum/barrier.
// k_main (cooperative, 256 blocks x 512 thr, 1 block/CU):
//   phase1: 4x64-row tiles: x->LDS bf16-hi, qkv GEMM (weights hoisted in regs),
//           rope/elu+1, q'->LDS, ksum/ctx accumulated in regs -> one atomic set.
//   grid barrier.
//   phase2: M = C@Wo in-LDS (split), out = (z .* q') @ M + bo.
// B=8 T=8192 DM=128 H=8 Dh=16.

typedef __attribute__((ext_vector_type(8))) short short8;   // 8 bf16 (MFMA A/B frag)
typedef __attribute__((ext_vector_type(4))) float floatx4;  // MFMA C/D frag

#define DEV __device__ __forceinline__
#define MFMA __builtin_amdgcn_mfma_f32_16x16x32_bf16

DEV unsigned short bfh(float f) {
  unsigned int x = __float_as_uint(f);
  x += 0x7fffu + ((x >> 16) & 1u);     // RNE
  return (unsigned short)(x >> 16);
}
DEV float bfdec(unsigned short u) { return __uint_as_float(((unsigned int)u) << 16); }
DEV void splitf(float f, unsigned short& h, unsigned short& l) {
  h = bfh(f);
  l = bfh(f - bfdec(h));
}

// Register transpose (verified R5-R10): C-layout tile val(n=lane16, m=mt*16+quad*4+r),
// rows m0/m1 -> split frag F[lane16][k=quad*8+j] over the 32-wide m-window.
DEV void xpose_frag(floatx4 m0, floatx4 m1, int lane16, int quad,
                    short8& hi, short8& lo) {
  union { short8 s; unsigned short u[8]; } H, L;
#pragma unroll
  for (int j = 0; j < 8; ++j) {
    int srcLane = lane16 + (((quad & 1) * 2 + (j >> 2)) << 4);
    float vA = __shfl(m0[j & 3], srcLane, 64);
    float vB = __shfl(m1[j & 3], srcLane, 64);
    float v = (quad < 2) ? vA : vB;
    splitf(v, H.u[j], L.u[j]);
  }
  hi = H.s; lo = L.s;
}

// ---------------- k_prep: W split-transpose + rope table + zero ctx/ksum/bar ----------------
__global__ void k_prep(const float* __restrict__ Wq, const float* __restrict__ Wk,
                       const float* __restrict__ Wv,
                       unsigned short* __restrict__ WTh, unsigned short* __restrict__ WTl,
                       float* __restrict__ ctxz, float2* __restrict__ ropeT) {
  int gid = blockIdx.x * 256 + threadIdx.x;
  if (gid < 6144) {               // 3 mats x 128 n x 16 k-groups of 8
    int mat = gid >> 11, r = gid & 2047, n = r >> 4, k0 = (r & 15) * 8;
    const float* W = (mat == 0) ? Wq : (mat == 1) ? Wk : Wv;
    union { uint4 q; unsigned short u[8]; } oh, ol;
#pragma unroll
    for (int i = 0; i < 8; ++i) splitf(W[(size_t)(k0 + i) * 128 + n], oh.u[i], ol.u[i]);
    *(uint4*)&WTh[mat * 16384 + n * 128 + k0] = oh.q;
    *(uint4*)&WTl[mat * 16384 + n * 128 + k0] = ol.q;
  } else if (gid < 6144 + 17424) {
    ctxz[gid - 6144] = 0.0f;      // ctx (16384) + ksum (1024) + barrier (16)
  } else if (gid < 6144 + 17424 + 65536) {
    int r = gid - 23568;          // (t,j): t = r>>3, j = r&7
    int t = r >> 3, j = r & 7;
    float invf = 1.0f / powf(10000.0f, (float)j * 0.125f);
    float s, c;
    sincosf((float)t * invf, &s, &c);
    ropeT[r] = make_float2(c, s);
  }
}

// ---------------- k_main: fused qkv+ctx | grid barrier | M + out ----------------
__global__ __launch_bounds__(512, 2) void k_main(
    const float* __restrict__ x, const float2* __restrict__ ropeT,
    const unsigned short* __restrict__ WTh, const unsigned short* __restrict__ WTl,
    const float* __restrict__ bq, const float* __restrict__ bk, const float* __restrict__ bv,
    const float* __restrict__ Wo, const float* __restrict__ bo,
    float* __restrict__ ctx, float* __restrict__ ksum, unsigned int* __restrict__ bar,
    float* __restrict__ out) {
  __shared__ unsigned short qS[256 * 136];       // q' bf16 [256 rows][128 + pad8]  (69.6 KB)
  __shared__ union {
    struct { unsigned short xh[64 * 136]; float rc[64][9]; float rs[64][9]; } p1;   // 22 KB
    struct { unsigned short mh[16384], ml[16384];                                    // 64 KB
             float ctxS[2048], ksumS[128], boS[128]; } p2;                           // +9 KB
  } U;                                           // union 73 KB; total ~142 KB -> 1 block/CU
  const int tid = threadIdx.x;
  const int row0 = blockIdx.x * 256;
  const int b = row0 >> 13;
  const int l = tid & 63, w = tid >> 6;          // wave w owns head w in phase 1
  const int lane16 = l & 15, quad = l >> 4;

  // ---------------- phase 1 ----------------
  // hoist all weight frags (constant across tiles): 24 x b128
  short8 wfh[4][3], wfl[4][3];
#pragma unroll
  for (int ks = 0; ks < 4; ++ks)
#pragma unroll
    for (int mat = 0; mat < 3; ++mat) {
      size_t off = (size_t)mat * 16384 + (size_t)(w * 16 + lane16) * 128 + ks * 32 + quad * 8;
      wfh[ks][mat] = *(const short8*)(WTh + off);
      wfl[ks][mat] = *(const short8*)(WTl + off);
    }
  const int col = w * 16 + lane16;
  const float biasq = bq[col], biask = bk[col], biasv = bv[col];

  float ksum_acc = 0.f;
  floatx4 ctxc = (floatx4){0.f, 0.f, 0.f, 0.f};

#pragma unroll 1
  for (int tile = 0; tile < 4; ++tile) {
    const int trow0 = row0 + tile * 64;
    const int t0 = trow0 & 8191;
    {  // rope slice
      int r = tid >> 3, j = tid & 7;
      float2 cs = ropeT[(t0 + r) * 8 + j];
      U.p1.rc[r][j] = cs.x; U.p1.rs[r][j] = cs.y;
    }
    {  // stage x as bf16-hi
      int r = tid >> 3, cg = (tid & 7) * 16;
      const float* xp = x + (size_t)(trow0 + r) * 128 + cg;
      float4 a = *(const float4*)xp;
      float4 b4 = *(const float4*)(xp + 4);
      float4 c4 = *(const float4*)(xp + 8);
      float4 d4 = *(const float4*)(xp + 12);
      float v[16] = {a.x, a.y, a.z, a.w, b4.x, b4.y, b4.z, b4.w,
                     c4.x, c4.y, c4.z, c4.w, d4.x, d4.y, d4.z, d4.w};
      union { short8 s; unsigned short u[8]; } h0, h1;
#pragma unroll
      for (int i = 0; i < 8; ++i) { h0.u[i] = bfh(v[i]); h1.u[i] = bfh(v[8 + i]); }
      *(short8*)&U.p1.xh[r * 136 + cg] = h0.s;
      *(short8*)&U.p1.xh[r * 136 + cg + 8] = h1.s;
    }
    __syncthreads();

    floatx4 acc[3][4];             // [mat: q,k,v][mt]
#pragma unroll
    for (int i = 0; i < 3; ++i)
#pragma unroll
      for (int j = 0; j < 4; ++j) acc[i][j] = (floatx4){0.f, 0.f, 0.f, 0.f};

#pragma unroll
    for (int ks = 0; ks < 4; ++ks) {
      short8 afh[4];
#pragma unroll
      for (int mt = 0; mt < 4; ++mt)
        afh[mt] = *(const short8*)&U.p1.xh[(mt * 16 + lane16) * 136 + ks * 32 + quad * 8];
#pragma unroll
      for (int mat = 0; mat < 3; ++mat)
#pragma unroll
        for (int mt = 0; mt < 4; ++mt) {
          acc[mat][mt] = MFMA(afh[mt], wfh[ks][mat], acc[mat][mt], 0, 0, 0);
          acc[mat][mt] = MFMA(afh[mt], wfl[ks][mat], acc[mat][mt], 0, 0, 0);
        }
    }

    // bias
#pragma unroll
    for (int mt = 0; mt < 4; ++mt)
#pragma unroll
      for (int r = 0; r < 4; ++r) {
        acc[0][mt][r] += biasq; acc[1][mt][r] += biask; acc[2][mt][r] += biasv;
      }

    // rope + elu+1 on q,k. lane16 = d; t = mt*16 + quad*4 + r.
    {
      const int d = lane16, j = d & 7;
#pragma unroll
      for (int mt = 0; mt < 4; ++mt) {
        float cc[4], ss[4];
#pragma unroll
        for (int r = 0; r < 4; ++r) {
          int tl = mt * 16 + quad * 4 + r;
          cc[r] = U.p1.rc[tl][j]; ss[r] = U.p1.rs[tl][j];
        }
#pragma unroll
        for (int mat = 0; mat < 2; ++mat)
#pragma unroll
          for (int r = 0; r < 4; ++r) {
            float v = acc[mat][mt][r];
            float p = __shfl_xor(v, 8);        // pair (d, d+8)
            float nv = (d < 8) ? (v * cc[r] - p * ss[r]) : (p * ss[r] + v * cc[r]);
            acc[mat][mt][r] = (nv > 0.f) ? (nv + 1.f) : __expf(nv);
          }
      }
    }

    // q' -> LDS (persistent)
#pragma unroll
    for (int mt = 0; mt < 4; ++mt)
#pragma unroll
      for (int r = 0; r < 4; ++r)
        qS[(tile * 64 + mt * 16 + quad * 4 + r) * 136 + col] = bfh(acc[0][mt][r]);

    // ksum partial (reduce at end)
#pragma unroll
    for (int mt = 0; mt < 4; ++mt)
#pragma unroll
      for (int r = 0; r < 4; ++r) ksum_acc += acc[1][mt][r];

    // ctx accumulate via register transposes
#pragma unroll
    for (int ks2 = 0; ks2 < 2; ++ks2) {
      short8 kh, kl, vh, vl;
      xpose_frag(acc[1][ks2 * 2], acc[1][ks2 * 2 + 1], lane16, quad, kh, kl);
      xpose_frag(acc[2][ks2 * 2], acc[2][ks2 * 2 + 1], lane16, quad, vh, vl);
      ctxc = MFMA(kh, vh, ctxc, 0, 0, 0);
      ctxc = MFMA(kl, vh, ctxc, 0, 0, 0);
      ctxc = MFMA(kh, vl, ctxc, 0, 0, 0);
    }
    __syncthreads();               // all xh/rc reads done before next restage
  }

  // ksum reduce + atomic
  {
    float s = ksum_acc;
    s += __shfl_xor(s, 16);
    s += __shfl_xor(s, 32);
    if (l < 16) atomicAdd(&ksum[(b * 8 + w) * 16 + lane16], s);
  }
  // ctx atomics
#pragma unroll
  for (int r = 0; r < 4; ++r)
    atomicAdd(&ctx[((size_t)(b * 8 + w) * 16 + quad * 4 + r) * 16 + lane16], ctxc[r]);

  // ---------------- grid barrier (cooperative: all 256 blocks resident) ----------------
  __threadfence();
  __syncthreads();
  if (tid == 0) {
    unsigned arrived =
        __hip_atomic_fetch_add(bar, 1u, __ATOMIC_ACQ_REL, __HIP_MEMORY_SCOPE_AGENT) + 1u;
    if (arrived == gridDim.x) {
      __hip_atomic_store(bar + 1, 1u, __ATOMIC_RELEASE, __HIP_MEMORY_SCOPE_AGENT);
    } else {
      while (__hip_atomic_load(bar + 1, __ATOMIC_ACQUIRE, __HIP_MEMORY_SCOPE_AGENT) == 0u)
        __builtin_amdgcn_s_sleep(32);
    }
  }
  __syncthreads();

  // ---------------- phase 2 ----------------
  {  // stage ctx/ksum via agent-scope loads (cross-XCD safe), bo plain
#pragma unroll
    for (int i = 0; i < 4; ++i)
      U.p2.ctxS[tid * 4 + i] = __hip_atomic_load(&ctx[(size_t)b * 2048 + tid * 4 + i],
                                                 __ATOMIC_RELAXED, __HIP_MEMORY_SCOPE_AGENT);
    if (tid < 128)
      U.p2.ksumS[tid] = __hip_atomic_load(&ksum[b * 128 + tid],
                                          __ATOMIC_RELAXED, __HIP_MEMORY_SCOPE_AGENT);
    else if (tid < 256)
      U.p2.boS[tid - 128] = bo[tid - 128];
  }
  __syncthreads();

  // M[qc][oc] = sum_e C_h[d][e] Wo[h*16+e][oc]; split -> mh/ml frag-major (R10-verified)
  {
    int oc = tid & 127;
    int qcg0 = (tid >> 7) * 4;
#pragma unroll
    for (int hh = 0; hh < 2; ++hh) {
      int h = (qcg0 >> 1) + hh;
      float m0[8] = {0, 0, 0, 0, 0, 0, 0, 0};
      float m1[8] = {0, 0, 0, 0, 0, 0, 0, 0};
#pragma unroll 4
      for (int e = 0; e < 16; ++e) {
        float wv = Wo[(size_t)(h * 16 + e) * 128 + oc];
        const float* cp = U.p2.ctxS + h * 256 + e;
#pragma unroll
        for (int i = 0; i < 8; ++i) {
          m0[i] += cp[i * 16] * wv;
          m1[i] += cp[(8 + i) * 16] * wv;
        }
      }
#pragma unroll
      for (int half = 0; half < 2; ++half) {
        int qcg = qcg0 + hh * 2 + half;
        const float* mm = half ? m1 : m0;
        union { uint4 q; unsigned short u[8]; } oh, ol;
#pragma unroll
        for (int i = 0; i < 8; ++i) splitf(mm[i], oh.u[i], ol.u[i]);
        int grp = (((oc >> 4) * 4 + (qcg >> 2)) * 64) + (qcg & 3) * 16 + (oc & 15);
        *(uint4*)&U.p2.mh[grp * 8] = oh.q;
        *(uint4*)&U.p2.ml[grp * 8] = ol.q;
      }
    }
  }
  __syncthreads();

  // out = (z .* q') @ M + bo. Wave w: rows w*32..w*32+31, 2 subtiles of 16.
#pragma unroll
  for (int mt2 = 0; mt2 < 2; ++mt2) {
    const int trowL = w * 32 + mt2 * 16 + lane16;      // lane16 = t (LDS row)
    short8 ah[4], al[4];
#pragma unroll
    for (int ks = 0; ks < 4; ++ks) {
      union { short8 s8; unsigned short u[8]; } qq;
      qq.s8 = *(const short8*)&qS[trowL * 136 + ks * 32 + quad * 8];
      int kb = ks * 32 + quad * 8;
      float s = 0.f;
#pragma unroll
      for (int j = 0; j < 8; ++j) s += bfdec(qq.u[j]) * U.p2.ksumS[kb + j];
      s += __shfl_xor(s, 16);      // combine the two 8-halves of the head
      float z = 1.0f / (s + 1e-6f);
      union { short8 s8; unsigned short u[8]; } H, L;
#pragma unroll
      for (int j = 0; j < 8; ++j) splitf(bfdec(qq.u[j]) * z, H.u[j], L.u[j]);
      ah[ks] = H.s8;
      al[ks] = L.s8;
    }

    floatx4 oacc[8];
#pragma unroll
    for (int j = 0; j < 8; ++j) oacc[j] = (floatx4){0.f, 0.f, 0.f, 0.f};
#pragma unroll
    for (int nt = 0; nt < 8; ++nt)
#pragma unroll
      for (int ks = 0; ks < 4; ++ks) {
        int moff = ((nt * 4 + ks) * 64 + l) * 8;       // frag-major: lane-contiguous 16B
        short8 wbh = *(const short8*)&U.p2.mh[moff];
        short8 wbl = *(const short8*)&U.p2.ml[moff];
        oacc[nt] = MFMA(ah[ks], wbh, oacc[nt], 0, 0, 0);
        oacc[nt] = MFMA(al[ks], wbh, oacc[nt], 0, 0, 0);
        oacc[nt] = MFMA(ah[ks], wbl, oacc[nt], 0, 0, 0);
      }

#pragma unroll
    for (int nt = 0; nt < 8; ++nt) {
      int oc = nt * 16 + lane16;
      float bb = U.p2.boS[oc];
#pragma unroll
      for (int r = 0; r < 4; ++r) {
        int t = row0 + w * 32 + mt2 * 16 + quad * 4 + r;
        out[(size_t)t * 128 + oc] = oacc[nt][r] + bb;
      }
    }
  }
}

extern "C" void kernel_launch(void* const* d_in, const int* in_sizes, int n_in,
                              void* d_out, int out_size, void* d_ws, size_t ws_size,
                              hipStream_t stream) {
  const float* x  = (const float*)d_in[0];
  const float* Wq = (const float*)d_in[1];
  const float* bq = (const float*)d_in[2];
  const float* Wk = (const float*)d_in[3];
  const float* bk = (const float*)d_in[4];
  const float* Wv = (const float*)d_in[5];
  const float* bv = (const float*)d_in[6];
  const float* Wo = (const float*)d_in[7];
  const float* bo = (const float*)d_in[8];
  float* out = (float*)d_out;

  // ws: WTh 96KB | WTl 96KB | ctx 64KB | ksum 4KB | bar 64B | ropeT 512KB  (~772 KB)
  unsigned short* WTh = (unsigned short*)d_ws;           // 3 x 16384
  unsigned short* WTl = WTh + 49152;
  float* ctx  = (float*)(WTl + 49152);                   // 16384 f
  float* ksum = ctx + 16384;                             // 1024 f
  unsigned int* bar = (unsigned int*)(ksum + 1024);      // 16 u32 (zeroed by k_prep)
  float2* ropeT = (float2*)((float*)bar + 16);           // 65536 float2

  k_prep<<<349, 256, 0, stream>>>(Wq, Wk, Wv, WTh, WTl, ctx, ropeT);

  void* args[] = {(void*)&x, (void*)&ropeT, (void*)&WTh, (void*)&WTl,
                  (void*)&bq, (void*)&bk, (void*)&bv, (void*)&Wo, (void*)&bo,
                  (void*)&ctx, (void*)&ksum, (void*)&bar, (void*)&out};
  hipLaunchCooperativeKernel((const void*)k_main, dim3(256), dim3(512), args, 0, stream);
}